// Round 1
// baseline (366.818 us; speedup 1.0000x reference)
//
#include <hip/hip_runtime.h>
#include <stdint.h>

#define T_TOK 2048
#define D_DIM 1024
#define H_DIM 2048
#define N_EXP 8
#define MAXS  5120   // max padded slots: 4096 + 8*127 = 5112 -> 5120

// workspace layout (bytes)
#define WS_CNT    0
#define WS_POFF   64
#define WS_BTOK   256
#define WS_BW     (WS_BTOK + N_EXP*2048*4)      // 65792
#define WS_XG     (WS_BW + N_EXP*2048*4)        // 131328 (16B aligned)
#define WS_HBUF   (WS_XG + (size_t)MAXS*1024*2) // + 10485760
#define WS_W1T    (WS_HBUF + (size_t)MAXS*2048*2)
#define WS_W2T    (WS_W1T + (size_t)N_EXP*1024*2048*2)

typedef __bf16 bf16x8 __attribute__((ext_vector_type(8)));
typedef float  f32x4  __attribute__((ext_vector_type(4)));

__device__ __forceinline__ unsigned short f2bf(float f) {
  unsigned int u = __float_as_uint(f);
  u += 0x7fffu + ((u >> 16) & 1u);   // round-to-nearest-even
  return (unsigned short)(u >> 16);
}

__device__ __forceinline__ float gelu_tanh(float x) {
  // jax.nn.gelu default: approximate=True (tanh form)
  float u = 0.7978845608028654f * (x + 0.044715f * x * x * x);
  return 0.5f * x * (1.0f + tanhf(u));
}

__global__ void zero_kernel(float4* __restrict__ out4, int* __restrict__ cnt) {
  int i = blockIdx.x * 256 + threadIdx.x;  // grid 2048*256*4 floats = T*D exactly
  out4[i] = make_float4(0.f, 0.f, 0.f, 0.f);
  if (blockIdx.x == 0 && threadIdx.x < N_EXP) cnt[threadIdx.x] = 0;
}

// one wave per token: logits = x @ Wg + bg; top-2; softmax; bucket scatter
__global__ void gate_kernel(const float* __restrict__ x, const float* __restrict__ Wg,
                            const float* __restrict__ bg, float* __restrict__ out_idx,
                            int* __restrict__ cnt, int* __restrict__ btok,
                            float* __restrict__ bw) {
  const int lane = threadIdx.x & 63;
  const int t = blockIdx.x * 4 + (threadIdx.x >> 6);
  float p[8];
#pragma unroll
  for (int i = 0; i < 8; ++i) p[i] = 0.f;
  const float* xr = x + (size_t)t * D_DIM;
  for (int i = lane; i < D_DIM; i += 64) {
    const float xv = xr[i];
    const float4 wa = ((const float4*)(Wg + i * 8))[0];
    const float4 wb = ((const float4*)(Wg + i * 8))[1];
    p[0] += xv * wa.x; p[1] += xv * wa.y; p[2] += xv * wa.z; p[3] += xv * wa.w;
    p[4] += xv * wb.x; p[5] += xv * wb.y; p[6] += xv * wb.z; p[7] += xv * wb.w;
  }
#pragma unroll
  for (int off = 32; off > 0; off >>= 1) {
#pragma unroll
    for (int i = 0; i < 8; ++i) p[i] += __shfl_xor(p[i], off);
  }
  if (lane == 0) {
#pragma unroll
    for (int i = 0; i < 8; ++i) p[i] += bg[i];
    int i0 = 0; float v0 = p[0];
#pragma unroll
    for (int i = 1; i < 8; ++i) if (p[i] > v0) { v0 = p[i]; i0 = i; }
    int i1 = -1; float v1 = -3.4e38f;
#pragma unroll
    for (int i = 0; i < 8; ++i) if (i != i0 && p[i] > v1) { v1 = p[i]; i1 = i; }
    const float ex = expf(v1 - v0);
    const float inv = 1.f / (1.f + ex);
    out_idx[t * 2 + 0] = (float)i0;   // top-k order: descending, ties -> lower idx
    out_idx[t * 2 + 1] = (float)i1;
    int s0 = atomicAdd(&cnt[i0], 1);
    btok[i0 * 2048 + s0] = t; bw[i0 * 2048 + s0] = inv;
    int s1 = atomicAdd(&cnt[i1], 1);
    btok[i1 * 2048 + s1] = t; bw[i1 * 2048 + s1] = ex * inv;
  }
}

__global__ void header_kernel(const int* __restrict__ cnt, int* __restrict__ poff) {
  if (threadIdx.x == 0) {
    int off = 0;
    for (int e = 0; e < N_EXP; ++e) { poff[e] = off; off += ((cnt[e] + 127) >> 7) << 7; }
    poff[N_EXP] = off;
  }
}

// fp32 [e][R][C] -> bf16 [e][C][R]  (weights become [n][k], B^T style)
__global__ void transpose_cvt(const float* __restrict__ in, unsigned short* __restrict__ out,
                              int R, int C) {
  __shared__ float tile[64][65];
  const size_t eo = (size_t)blockIdx.z * R * C;
  const int c0 = blockIdx.x * 64;
  const int r0 = blockIdx.y * 64;
  for (int i = threadIdx.x; i < 4096; i += 256) {
    const int r = i >> 6, c = i & 63;
    tile[r][c] = in[eo + (size_t)(r0 + r) * C + (c0 + c)];
  }
  __syncthreads();
  for (int i = threadIdx.x; i < 4096; i += 256) {
    const int cc = i >> 6, rr = i & 63;
    out[eo + (size_t)(c0 + cc) * R + (r0 + rr)] = f2bf(tile[rr][cc]);
  }
}

// one block per padded slot row: gather routed token row fp32 -> bf16 (pad rows = 0)
__global__ void gather_cvt(const float* __restrict__ x, const int* __restrict__ poff,
                           const int* __restrict__ cnt, const int* __restrict__ btok,
                           unsigned short* __restrict__ Xg) {
  const int s = blockIdx.x;
  if (s >= poff[N_EXP]) return;
  int e = 0;
#pragma unroll
  for (int i = 0; i < N_EXP; ++i) if (s >= poff[i + 1]) e = i + 1;
  const int local = s - poff[e];
  uint2* orow = (uint2*)(Xg + (size_t)s * D_DIM);
  if (local < cnt[e]) {
    const int t = btok[e * 2048 + local];
    const float4 v = ((const float4*)(x + (size_t)t * D_DIM))[threadIdx.x];
    uint2 u;
    u.x = (unsigned)f2bf(v.x) | ((unsigned)f2bf(v.y) << 16);
    u.y = (unsigned)f2bf(v.z) | ((unsigned)f2bf(v.w) << 16);
    orow[threadIdx.x] = u;
  } else {
    orow[threadIdx.x] = make_uint2(0u, 0u);
  }
}

// MODE 0: Hbuf[s][n] = gelu(Xg[s] @ W1t[e]^T + b1[e])     (K=1024, N=2048)
// MODE 1: out[tok]  += w_s * (Hbuf[s] @ W2t[e]^T + b2[e]) (K=2048, N=1024), atomic
template <int MODE>
__global__ void __launch_bounds__(256) moe_gemm(
    const unsigned short* __restrict__ A, const unsigned short* __restrict__ B,
    const float* __restrict__ bias, const int* __restrict__ poff,
    const int* __restrict__ cnt, const int* __restrict__ btok,
    const float* __restrict__ bw, unsigned short* __restrict__ Hout,
    float* __restrict__ out) {
  constexpr int K = (MODE == 0) ? D_DIM : H_DIM;

  const int e = blockIdx.y >> 4;
  const int mt = blockIdx.y & 15;
  const int base = poff[e];
  const int pcnt = poff[e + 1] - base;
  if (mt * 128 >= pcnt) return;
  const int row0 = base + mt * 128;
  const int n0 = blockIdx.x * 128;

  __shared__ __align__(16) unsigned short As[128 * 32];
  __shared__ __align__(16) unsigned short Bs[128 * 32];

  const int tid = threadIdx.x;
  const int lane = tid & 63;
  const int wv = tid >> 6;
  const int wm = wv >> 1;
  const int wn = wv & 1;

  const unsigned short* Ab = A + (size_t)row0 * K;
  const unsigned short* Bb = B + (size_t)e * ((size_t)H_DIM * D_DIM) + (size_t)n0 * K;

  f32x4 acc[4][4];
#pragma unroll
  for (int i = 0; i < 4; ++i)
#pragma unroll
    for (int j = 0; j < 4; ++j) acc[i][j] = (f32x4)(0.0f);

  const int subr = lane >> 2;        // 0..15
  const int ks = (lane & 3) * 8;     // 0,8,16,24
  const int fr = lane & 15;
  const int kq = (lane >> 4) * 8;

  for (int kt = 0; kt < K / 32; ++kt) {
    const int k0 = kt * 32;
#pragma unroll
    for (int it = 0; it < 2; ++it) {
      const int ci = wv + it * 4;            // 0..7, 16 rows each
      const int r = ci * 16 + subr;
      const unsigned short* ga = Ab + (size_t)r * K + (k0 + ks);
      const unsigned short* gb = Bb + (size_t)r * K + (k0 + ks);
      __builtin_amdgcn_global_load_lds(
          (__attribute__((address_space(1))) void*)ga,
          (__attribute__((address_space(3))) void*)(As + ci * 16 * 32), 16, 0, 0);
      __builtin_amdgcn_global_load_lds(
          (__attribute__((address_space(1))) void*)gb,
          (__attribute__((address_space(3))) void*)(Bs + ci * 16 * 32), 16, 0, 0);
    }
    __syncthreads();
    bf16x8 av[4], bv[4];
#pragma unroll
    for (int mi = 0; mi < 4; ++mi)
      av[mi] = *(const bf16x8*)(As + (wm * 64 + mi * 16 + fr) * 32 + kq);
#pragma unroll
    for (int ni = 0; ni < 4; ++ni)
      bv[ni] = *(const bf16x8*)(Bs + (wn * 64 + ni * 16 + fr) * 32 + kq);
#pragma unroll
    for (int mi = 0; mi < 4; ++mi)
#pragma unroll
      for (int ni = 0; ni < 4; ++ni)
        acc[mi][ni] = __builtin_amdgcn_mfma_f32_16x16x32_bf16(av[mi], bv[ni], acc[mi][ni], 0, 0, 0);
    __syncthreads();
  }

  if (MODE == 0) {
    const float* bb = bias + (size_t)e * H_DIM + n0;
#pragma unroll
    for (int mi = 0; mi < 4; ++mi) {
      const int rb = wm * 64 + mi * 16 + (lane >> 4) * 4;
#pragma unroll
      for (int r = 0; r < 4; ++r) {
        unsigned short* hp = Hout + (size_t)(row0 + rb + r) * H_DIM + n0;
#pragma unroll
        for (int ni = 0; ni < 4; ++ni) {
          const int col = wn * 64 + ni * 16 + fr;
          hp[col] = f2bf(gelu_tanh(acc[mi][ni][r] + bb[col]));
        }
      }
    }
  } else {
    const float* bb = bias + (size_t)e * D_DIM + n0;
    const int ce = cnt[e];
#pragma unroll
    for (int mi = 0; mi < 4; ++mi) {
      const int rb = wm * 64 + mi * 16 + (lane >> 4) * 4;
#pragma unroll
      for (int r = 0; r < 4; ++r) {
        const int local = mt * 128 + rb + r;
        if (local < ce) {
          const int tok = btok[e * 2048 + local];
          const float w = bw[e * 2048 + local];
          float* op = out + (size_t)tok * D_DIM + n0;
#pragma unroll
          for (int ni = 0; ni < 4; ++ni) {
            const int col = wn * 64 + ni * 16 + fr;
            atomicAdd(op + col, w * (acc[mi][ni][r] + bb[col]));
          }
        }
      }
    }
  }
}

extern "C" void kernel_launch(void* const* d_in, const int* in_sizes, int n_in,
                              void* d_out, int out_size, void* d_ws, size_t ws_size,
                              hipStream_t stream) {
  const float* moe_inp = (const float*)d_in[0];
  const float* Wg = (const float*)d_in[1];
  const float* bg = (const float*)d_in[2];
  const float* W1 = (const float*)d_in[3];
  const float* b1 = (const float*)d_in[4];
  const float* W2 = (const float*)d_in[5];
  const float* b2 = (const float*)d_in[6];
  float* out = (float*)d_out;

  char* ws = (char*)d_ws;
  int* cnt  = (int*)(ws + WS_CNT);
  int* poff = (int*)(ws + WS_POFF);
  int* btok = (int*)(ws + WS_BTOK);
  float* bw = (float*)(ws + WS_BW);
  unsigned short* Xg   = (unsigned short*)(ws + WS_XG);
  unsigned short* Hbuf = (unsigned short*)(ws + WS_HBUF);
  unsigned short* W1t  = (unsigned short*)(ws + WS_W1T);
  unsigned short* W2t  = (unsigned short*)(ws + WS_W2T);

  zero_kernel<<<dim3(2048), dim3(256), 0, stream>>>((float4*)out, cnt);
  gate_kernel<<<dim3(T_TOK / 4), dim3(256), 0, stream>>>(moe_inp, Wg, bg,
                                                         out + (size_t)T_TOK * D_DIM,
                                                         cnt, btok, bw);
  header_kernel<<<dim3(1), dim3(64), 0, stream>>>(cnt, poff);
  // W1 [e][1024][2048] -> W1t [e][2048][1024]
  transpose_cvt<<<dim3(H_DIM / 64, D_DIM / 64, N_EXP), dim3(256), 0, stream>>>(W1, W1t, D_DIM, H_DIM);
  // W2 [e][2048][1024] -> W2t [e][1024][2048]
  transpose_cvt<<<dim3(D_DIM / 64, H_DIM / 64, N_EXP), dim3(256), 0, stream>>>(W2, W2t, H_DIM, D_DIM);
  gather_cvt<<<dim3(MAXS), dim3(256), 0, stream>>>(moe_inp, poff, cnt, btok, Xg);
  moe_gemm<0><<<dim3(H_DIM / 128, N_EXP * 16), dim3(256), 0, stream>>>(
      Xg, W1t, b1, poff, cnt, btok, bw, Hbuf, nullptr);
  moe_gemm<1><<<dim3(D_DIM / 128, N_EXP * 16), dim3(256), 0, stream>>>(
      Hbuf, W2t, b2, poff, cnt, btok, bw, nullptr, out);
}

// Round 2
// 348.845 us; speedup vs baseline: 1.0515x; 1.0515x over previous
//
#include <hip/hip_runtime.h>
#include <stdint.h>

#define T_TOK 2048
#define D_DIM 1024
#define H_DIM 2048
#define N_EXP 8
#define MAXS  5120   // max padded slots: 4096 + 8*127 = 5112 -> 5120

// workspace layout (bytes)
#define WS_CNT    0
#define WS_POFF   64
#define WS_BTOK   256
#define WS_BW     (WS_BTOK + N_EXP*2048*4)      // 65792
#define WS_XG     (WS_BW + N_EXP*2048*4)        // 131328 (16B aligned)
#define WS_HBUF   (WS_XG + (size_t)MAXS*1024*2) // + 10485760
#define WS_W1T    (WS_HBUF + (size_t)MAXS*2048*2)
#define WS_W2T    (WS_W1T + (size_t)N_EXP*1024*2048*2)

typedef __bf16 bf16x8 __attribute__((ext_vector_type(8)));
typedef float  f32x4  __attribute__((ext_vector_type(4)));

__device__ __forceinline__ unsigned short f2bf(float f) {
  unsigned int u = __float_as_uint(f);
  u += 0x7fffu + ((u >> 16) & 1u);   // round-to-nearest-even
  return (unsigned short)(u >> 16);
}

__device__ __forceinline__ float gelu_tanh(float x) {
  float u = 0.7978845608028654f * (x + 0.044715f * x * x * x);
  return 0.5f * x * (1.0f + tanhf(u));
}

__global__ void zero_kernel(float4* __restrict__ out4, int* __restrict__ cnt) {
  int i = blockIdx.x * 256 + threadIdx.x;  // 2048 blocks * 256 * 4 floats = T*D
  out4[i] = make_float4(0.f, 0.f, 0.f, 0.f);
  if (blockIdx.x == 0 && threadIdx.x < N_EXP) cnt[threadIdx.x] = 0;
}

// one wave per token: logits = x @ Wg + bg; top-2; softmax; bucket scatter
__global__ void gate_kernel(const float* __restrict__ x, const float* __restrict__ Wg,
                            const float* __restrict__ bg, float* __restrict__ out_idx,
                            int* __restrict__ cnt, int* __restrict__ btok,
                            float* __restrict__ bw) {
  const int lane = threadIdx.x & 63;
  const int t = blockIdx.x * 4 + (threadIdx.x >> 6);
  float p[8];
#pragma unroll
  for (int i = 0; i < 8; ++i) p[i] = 0.f;
  const float* xr = x + (size_t)t * D_DIM;
  for (int i = lane; i < D_DIM; i += 64) {
    const float xv = xr[i];
    const float4 wa = ((const float4*)(Wg + i * 8))[0];
    const float4 wb = ((const float4*)(Wg + i * 8))[1];
    p[0] += xv * wa.x; p[1] += xv * wa.y; p[2] += xv * wa.z; p[3] += xv * wa.w;
    p[4] += xv * wb.x; p[5] += xv * wb.y; p[6] += xv * wb.z; p[7] += xv * wb.w;
  }
#pragma unroll
  for (int off = 32; off > 0; off >>= 1) {
#pragma unroll
    for (int i = 0; i < 8; ++i) p[i] += __shfl_xor(p[i], off);
  }
  if (lane == 0) {
#pragma unroll
    for (int i = 0; i < 8; ++i) p[i] += bg[i];
    int i0 = 0; float v0 = p[0];
#pragma unroll
    for (int i = 1; i < 8; ++i) if (p[i] > v0) { v0 = p[i]; i0 = i; }
    int i1 = -1; float v1 = -3.4e38f;
#pragma unroll
    for (int i = 0; i < 8; ++i) if (i != i0 && p[i] > v1) { v1 = p[i]; i1 = i; }
    const float ex = expf(v1 - v0);
    const float inv = 1.f / (1.f + ex);
    out_idx[t * 2 + 0] = (float)i0;
    out_idx[t * 2 + 1] = (float)i1;
    int s0 = atomicAdd(&cnt[i0], 1);
    btok[i0 * 2048 + s0] = t; bw[i0 * 2048 + s0] = inv;
    int s1 = atomicAdd(&cnt[i1], 1);
    btok[i1 * 2048 + s1] = t; bw[i1 * 2048 + s1] = ex * inv;
  }
}

__global__ void header_kernel(const int* __restrict__ cnt, int* __restrict__ poff) {
  if (threadIdx.x == 0) {
    int off = 0;
    for (int e = 0; e < N_EXP; ++e) { poff[e] = off; off += ((cnt[e] + 127) >> 7) << 7; }
    poff[N_EXP] = off;
  }
}

// Both weight transposes in one launch. set 0: W1 [e][1024][2048] -> [e][2048][1024]
//                                      set 1: W2 [e][2048][1024] -> [e][1024][2048]
// float4 global reads; 16B packed-bf16 stores (was 2B/lane scalar).
__global__ void transpose_cvt(const float* __restrict__ W1, unsigned short* __restrict__ W1t,
                              const float* __restrict__ W2, unsigned short* __restrict__ W2t) {
  const int set = blockIdx.z;
  const int e = blockIdx.y;
  const int lin = blockIdx.x;               // 0..511
  const int R = set ? H_DIM : D_DIM;
  const int C = set ? D_DIM : H_DIM;
  const int tx = set ? (lin & 15) : (lin & 31);
  const int ty = set ? (lin >> 4) : (lin >> 5);
  const float* in = (set ? W2 : W1) + (size_t)e * (D_DIM * H_DIM);
  unsigned short* out = (set ? W2t : W1t) + (size_t)e * (D_DIM * H_DIM);
  const int c0 = tx * 64, r0 = ty * 64;
  __shared__ float tile[64][68];
  const int tid = threadIdx.x;
#pragma unroll
  for (int p = 0; p < 4; ++p) {
    const int idx = p * 256 + tid;
    const int r = idx >> 4, c4 = idx & 15;
    *(float4*)&tile[r][c4 * 4] = *(const float4*)(in + (size_t)(r0 + r) * C + c0 + c4 * 4);
  }
  __syncthreads();
#pragma unroll
  for (int p = 0; p < 2; ++p) {
    const int idx = p * 256 + tid;
    const int oc = idx >> 3, seg = idx & 7;
    unsigned u[4];
#pragma unroll
    for (int j = 0; j < 4; ++j) {
      const unsigned lo = f2bf(tile[seg * 8 + 2 * j][oc]);
      const unsigned hi = f2bf(tile[seg * 8 + 2 * j + 1][oc]);
      u[j] = lo | (hi << 16);
    }
    *(uint4*)(out + (size_t)(c0 + oc) * R + r0 + seg * 8) = make_uint4(u[0], u[1], u[2], u[3]);
  }
}

// one block per padded slot row: gather routed token row fp32 -> bf16 (pad rows = 0)
__global__ void gather_cvt(const float* __restrict__ x, const int* __restrict__ poff,
                           const int* __restrict__ cnt, const int* __restrict__ btok,
                           unsigned short* __restrict__ Xg) {
  const int s = blockIdx.x;
  if (s >= poff[N_EXP]) return;
  int e = 0;
#pragma unroll
  for (int i = 0; i < N_EXP; ++i) if (s >= poff[i + 1]) e = i + 1;
  const int local = s - poff[e];
  uint2* orow = (uint2*)(Xg + (size_t)s * D_DIM);
  if (local < cnt[e]) {
    const int t = btok[e * 2048 + local];
    const float4 v = ((const float4*)(x + (size_t)t * D_DIM))[threadIdx.x];
    uint2 u;
    u.x = (unsigned)f2bf(v.x) | ((unsigned)f2bf(v.y) << 16);
    u.y = (unsigned)f2bf(v.z) | ((unsigned)f2bf(v.w) << 16);
    orow[threadIdx.x] = u;
  } else {
    orow[threadIdx.x] = make_uint2(0u, 0u);
  }
}

// MODE 0: Hbuf[s][n] = gelu(Xg[s] @ W1t[e]^T + b1[e])     (K=1024, N=2048, SK=1)
// MODE 1: out[tok]  += w_s * (Hbuf[s] @ W2t[e]^T + b2[e]) (K=2048, N=1024, SK=2, atomic)
// Double-buffered LDS, one barrier per K-iter, XCD-swizzled grid (m-blocks of a
// (n,e,kslice) group land on one XCD so B-strips are L2-resident).
template <int MODE>
__global__ void __launch_bounds__(256) moe_gemm(
    const unsigned short* __restrict__ A, const unsigned short* __restrict__ B,
    const float* __restrict__ bias, const int* __restrict__ poff,
    const int* __restrict__ cnt, const int* __restrict__ btok,
    const float* __restrict__ bw, unsigned short* __restrict__ Hout,
    float* __restrict__ out) {
  constexpr int K   = (MODE == 0) ? D_DIM : H_DIM;
  constexpr int NT  = (MODE == 0) ? H_DIM / 128 : D_DIM / 128;
  constexpr int SK  = (MODE == 0) ? 1 : 2;
  constexpr int KS  = K / SK;
  constexpr int NIT = KS / 32;

  // decode swizzled linear index: lin = ghi*128 + m*8 + glo ; g = ghi*8 + glo
  const int lin  = blockIdx.x;
  const int glo  = lin & 7;
  const int mt   = (lin >> 3) & 15;
  const int g    = ((lin >> 7) << 3) | glo;
  const int nt   = g % NT;
  const int rest = g / NT;
  const int e    = rest & 7;
  const int ksl  = rest >> 3;

  const int base = poff[e];
  const int pcnt = poff[e + 1] - base;
  if (mt * 128 >= pcnt) return;
  const int row0 = base + mt * 128;
  const int n0 = nt * 128;

  __shared__ __align__(16) unsigned short As[2][128 * 32];
  __shared__ __align__(16) unsigned short Bs[2][128 * 32];

  const int tid = threadIdx.x;
  const int lane = tid & 63;
  const int wv = tid >> 6;
  const int wm = wv >> 1;
  const int wn = wv & 1;

  const unsigned short* Ab = A + (size_t)row0 * K + ksl * KS;
  const unsigned short* Bb = B + (size_t)e * ((size_t)H_DIM * D_DIM) + (size_t)n0 * K + ksl * KS;

  f32x4 acc[4][4];
#pragma unroll
  for (int i = 0; i < 4; ++i)
#pragma unroll
    for (int j = 0; j < 4; ++j) acc[i][j] = (f32x4)(0.0f);

  const int subr = lane >> 2;        // 0..15
  const int ks = (lane & 3) * 8;     // 0,8,16,24
  const int fr = lane & 15;
  const int kq = (lane >> 4) * 8;

  auto stage = [&](int kt, int b) {
    const int k0 = kt * 32;
#pragma unroll
    for (int it = 0; it < 2; ++it) {
      const int ci = wv + it * 4;            // 0..7, 16 rows each
      const int r = ci * 16 + subr;
      const unsigned short* ga = Ab + (size_t)r * K + (k0 + ks);
      const unsigned short* gb = Bb + (size_t)r * K + (k0 + ks);
      __builtin_amdgcn_global_load_lds(
          (__attribute__((address_space(1))) void*)ga,
          (__attribute__((address_space(3))) void*)(As[b] + ci * 16 * 32), 16, 0, 0);
      __builtin_amdgcn_global_load_lds(
          (__attribute__((address_space(1))) void*)gb,
          (__attribute__((address_space(3))) void*)(Bs[b] + ci * 16 * 32), 16, 0, 0);
    }
  };

  stage(0, 0);
  for (int i = 0; i < NIT; ++i) {
    const int b = i & 1;
    __syncthreads();                    // drains prefetch into buf b; protects WAR on buf b^1
    if (i + 1 < NIT) stage(i + 1, b ^ 1);
    bf16x8 av[4], bv[4];
#pragma unroll
    for (int mi = 0; mi < 4; ++mi)
      av[mi] = *(const bf16x8*)(As[b] + (wm * 64 + mi * 16 + fr) * 32 + kq);
#pragma unroll
    for (int ni = 0; ni < 4; ++ni)
      bv[ni] = *(const bf16x8*)(Bs[b] + (wn * 64 + ni * 16 + fr) * 32 + kq);
#pragma unroll
    for (int mi = 0; mi < 4; ++mi)
#pragma unroll
      for (int ni = 0; ni < 4; ++ni)
        acc[mi][ni] = __builtin_amdgcn_mfma_f32_16x16x32_bf16(av[mi], bv[ni], acc[mi][ni], 0, 0, 0);
  }

  if (MODE == 0) {
    const float* bb = bias + (size_t)e * H_DIM + n0;
#pragma unroll
    for (int mi = 0; mi < 4; ++mi) {
      const int rb = wm * 64 + mi * 16 + (lane >> 4) * 4;
#pragma unroll
      for (int r = 0; r < 4; ++r) {
        unsigned short* hp = Hout + (size_t)(row0 + rb + r) * H_DIM + n0;
#pragma unroll
        for (int ni = 0; ni < 4; ++ni) {
          const int col = wn * 64 + ni * 16 + fr;
          hp[col] = f2bf(gelu_tanh(acc[mi][ni][r] + bb[col]));
        }
      }
    }
  } else {
    const float* bb = bias + (size_t)e * D_DIM + n0;
    const int ce = cnt[e];
#pragma unroll
    for (int mi = 0; mi < 4; ++mi) {
      const int rb = wm * 64 + mi * 16 + (lane >> 4) * 4;
#pragma unroll
      for (int r = 0; r < 4; ++r) {
        const int local = mt * 128 + rb + r;
        if (local < ce) {
          const int tok = btok[e * 2048 + local];
          const float w = bw[e * 2048 + local];
          float* op = out + (size_t)tok * D_DIM + n0;
#pragma unroll
          for (int ni = 0; ni < 4; ++ni) {
            const int col = wn * 64 + ni * 16 + fr;
            const float bias_once = (ksl == 0) ? bb[col] : 0.f;
            atomicAdd(op + col, w * (acc[mi][ni][r] + bias_once));
          }
        }
      }
    }
  }
}

extern "C" void kernel_launch(void* const* d_in, const int* in_sizes, int n_in,
                              void* d_out, int out_size, void* d_ws, size_t ws_size,
                              hipStream_t stream) {
  const float* moe_inp = (const float*)d_in[0];
  const float* Wg = (const float*)d_in[1];
  const float* bg = (const float*)d_in[2];
  const float* W1 = (const float*)d_in[3];
  const float* b1 = (const float*)d_in[4];
  const float* W2 = (const float*)d_in[5];
  const float* b2 = (const float*)d_in[6];
  float* out = (float*)d_out;

  char* ws = (char*)d_ws;
  int* cnt  = (int*)(ws + WS_CNT);
  int* poff = (int*)(ws + WS_POFF);
  int* btok = (int*)(ws + WS_BTOK);
  float* bw = (float*)(ws + WS_BW);
  unsigned short* Xg   = (unsigned short*)(ws + WS_XG);
  unsigned short* Hbuf = (unsigned short*)(ws + WS_HBUF);
  unsigned short* W1t  = (unsigned short*)(ws + WS_W1T);
  unsigned short* W2t  = (unsigned short*)(ws + WS_W2T);

  zero_kernel<<<dim3(2048), dim3(256), 0, stream>>>((float4*)out, cnt);
  gate_kernel<<<dim3(T_TOK / 4), dim3(256), 0, stream>>>(moe_inp, Wg, bg,
                                                         out + (size_t)T_TOK * D_DIM,
                                                         cnt, btok, bw);
  header_kernel<<<dim3(1), dim3(64), 0, stream>>>(cnt, poff);
  transpose_cvt<<<dim3(512, N_EXP, 2), dim3(256), 0, stream>>>(W1, W1t, W2, W2t);
  gather_cvt<<<dim3(MAXS), dim3(256), 0, stream>>>(moe_inp, poff, cnt, btok, Xg);
  // grid.x = 16 m-tiles * NT * 8 experts * SK = 2048 for both modes
  moe_gemm<0><<<dim3(2048), dim3(256), 0, stream>>>(
      Xg, W1t, b1, poff, cnt, btok, bw, Hbuf, nullptr);
  moe_gemm<1><<<dim3(2048), dim3(256), 0, stream>>>(
      Hbuf, W2t, b2, poff, cnt, btok, bw, nullptr, out);
}

// Round 3
// 339.813 us; speedup vs baseline: 1.0795x; 1.0266x over previous
//
#include <hip/hip_runtime.h>
#include <stdint.h>

#define T_TOK 2048
#define D_DIM 1024
#define H_DIM 2048
#define N_EXP 8
#define MAXS  4608   // max padded slots: 4096 + 8*63 = 4600 -> 4608

// workspace layout (bytes)
#define WS_CNT    0
#define WS_BTOK   256
#define WS_BW     (WS_BTOK + N_EXP*2048*4)
#define WS_XG     (WS_BW + N_EXP*2048*4)        // 16B aligned
#define WS_HBUF   (WS_XG + (size_t)MAXS*1024*2)
#define WS_W1T    (WS_HBUF + (size_t)MAXS*2048*2)
#define WS_W2T    (WS_W1T + (size_t)N_EXP*1024*2048*2)

typedef __bf16 bf16x8 __attribute__((ext_vector_type(8)));
typedef float  f32x4  __attribute__((ext_vector_type(4)));

__device__ __forceinline__ unsigned short f2bf(float f) {
  unsigned int u = __float_as_uint(f);
  u += 0x7fffu + ((u >> 16) & 1u);   // round-to-nearest-even
  return (unsigned short)(u >> 16);
}

__device__ __forceinline__ float gelu_tanh(float x) {
  float u = 0.7978845608028654f * (x + 0.044715f * x * x * x);
  return 0.5f * x * (1.0f + tanhf(u));
}

__global__ void zero_kernel(float4* __restrict__ out4, int* __restrict__ cnt) {
  int i = blockIdx.x * 256 + threadIdx.x;  // 2048 blocks * 256 * 4 floats = T*D
  out4[i] = make_float4(0.f, 0.f, 0.f, 0.f);
  if (blockIdx.x == 0 && threadIdx.x < N_EXP) cnt[threadIdx.x] = 0;
}

// one wave per token: logits = x @ Wg + bg; top-2; softmax; bucket scatter
__global__ void gate_kernel(const float* __restrict__ x, const float* __restrict__ Wg,
                            const float* __restrict__ bg, float* __restrict__ out_idx,
                            int* __restrict__ cnt, int* __restrict__ btok,
                            float* __restrict__ bw) {
  const int lane = threadIdx.x & 63;
  const int t = blockIdx.x * 4 + (threadIdx.x >> 6);
  float p[8];
#pragma unroll
  for (int i = 0; i < 8; ++i) p[i] = 0.f;
  const float* xr = x + (size_t)t * D_DIM;
  for (int i = lane; i < D_DIM; i += 64) {
    const float xv = xr[i];
    const float4 wa = ((const float4*)(Wg + i * 8))[0];
    const float4 wb = ((const float4*)(Wg + i * 8))[1];
    p[0] += xv * wa.x; p[1] += xv * wa.y; p[2] += xv * wa.z; p[3] += xv * wa.w;
    p[4] += xv * wb.x; p[5] += xv * wb.y; p[6] += xv * wb.z; p[7] += xv * wb.w;
  }
#pragma unroll
  for (int off = 32; off > 0; off >>= 1) {
#pragma unroll
    for (int i = 0; i < 8; ++i) p[i] += __shfl_xor(p[i], off);
  }
  if (lane == 0) {
#pragma unroll
    for (int i = 0; i < 8; ++i) p[i] += bg[i];
    int i0 = 0; float v0 = p[0];
#pragma unroll
    for (int i = 1; i < 8; ++i) if (p[i] > v0) { v0 = p[i]; i0 = i; }
    int i1 = -1; float v1 = -3.4e38f;
#pragma unroll
    for (int i = 0; i < 8; ++i) if (i != i0 && p[i] > v1) { v1 = p[i]; i1 = i; }
    const float ex = expf(v1 - v0);
    const float inv = 1.f / (1.f + ex);
    out_idx[t * 2 + 0] = (float)i0;
    out_idx[t * 2 + 1] = (float)i1;
    int s0 = atomicAdd(&cnt[i0], 1);
    btok[i0 * 2048 + s0] = t; bw[i0 * 2048 + s0] = inv;
    int s1 = atomicAdd(&cnt[i1], 1);
    btok[i1 * 2048 + s1] = t; bw[i1 * 2048 + s1] = ex * inv;
  }
}

// Both weight transposes in one launch. set 0: W1 [e][1024][2048] -> [e][2048][1024]
//                                      set 1: W2 [e][2048][1024] -> [e][1024][2048]
__global__ void transpose_cvt(const float* __restrict__ W1, unsigned short* __restrict__ W1t,
                              const float* __restrict__ W2, unsigned short* __restrict__ W2t) {
  const int set = blockIdx.z;
  const int e = blockIdx.y;
  const int lin = blockIdx.x;               // 0..511
  const int R = set ? H_DIM : D_DIM;
  const int C = set ? D_DIM : H_DIM;
  const int tx = set ? (lin & 15) : (lin & 31);
  const int ty = set ? (lin >> 4) : (lin >> 5);
  const float* in = (set ? W2 : W1) + (size_t)e * (D_DIM * H_DIM);
  unsigned short* out = (set ? W2t : W1t) + (size_t)e * (D_DIM * H_DIM);
  const int c0 = tx * 64, r0 = ty * 64;
  __shared__ float tile[64][68];
  const int tid = threadIdx.x;
#pragma unroll
  for (int p = 0; p < 4; ++p) {
    const int idx = p * 256 + tid;
    const int r = idx >> 4, c4 = idx & 15;
    *(float4*)&tile[r][c4 * 4] = *(const float4*)(in + (size_t)(r0 + r) * C + c0 + c4 * 4);
  }
  __syncthreads();
#pragma unroll
  for (int p = 0; p < 2; ++p) {
    const int idx = p * 256 + tid;
    const int oc = idx >> 3, seg = idx & 7;
    unsigned u[4];
#pragma unroll
    for (int j = 0; j < 4; ++j) {
      const unsigned lo = f2bf(tile[seg * 8 + 2 * j][oc]);
      const unsigned hi = f2bf(tile[seg * 8 + 2 * j + 1][oc]);
      u[j] = lo | (hi << 16);
    }
    *(uint4*)(out + (size_t)(c0 + oc) * R + r0 + seg * 8) = make_uint4(u[0], u[1], u[2], u[3]);
  }
}

// inline padded prefix over the 8 expert counts (replaces header kernel)
__device__ __forceinline__ void expert_seg(const int* __restrict__ cnt, int e,
                                           int& base, int& ce, int& pcnt, int& total) {
  int off = 0; base = 0; ce = 0; pcnt = 0;
#pragma unroll
  for (int i = 0; i < N_EXP; ++i) {
    const int c = cnt[i];
    const int p = (c + 63) & ~63;
    if (i == e) { base = off; ce = c; pcnt = p; }
    off += p;
  }
  total = off;
}

// one block per padded slot row: gather routed token row fp32 -> bf16 (pad rows = 0)
__global__ void gather_cvt(const float* __restrict__ x, const int* __restrict__ cnt,
                           const int* __restrict__ btok, unsigned short* __restrict__ Xg) {
  const int s = blockIdx.x;
  int off = 0, e = -1, loc = 0, c_e = 0;
#pragma unroll
  for (int i = 0; i < N_EXP; ++i) {
    const int c = cnt[i];
    const int p = (c + 63) & ~63;
    if (e < 0 && s < off + p) { e = i; loc = s - off; c_e = c; }
    off += p;
  }
  if (e < 0) return;  // beyond total padded slots
  uint2* orow = (uint2*)(Xg + (size_t)s * D_DIM);
  if (loc < c_e) {
    const int t = btok[e * 2048 + loc];
    const float4 v = ((const float4*)(x + (size_t)t * D_DIM))[threadIdx.x];
    uint2 u;
    u.x = (unsigned)f2bf(v.x) | ((unsigned)f2bf(v.y) << 16);
    u.y = (unsigned)f2bf(v.z) | ((unsigned)f2bf(v.w) << 16);
    orow[threadIdx.x] = u;
  } else {
    orow[threadIdx.x] = make_uint2(0u, 0u);
  }
}

// MODE 0: Hbuf[s][n] = gelu(Xg[s] @ W1t[e]^T + b1[e])     (K=1024, N=2048, SK=1)
// MODE 1: out[tok]  += w_s * (Hbuf[s] @ W2t[e]^T + b2[e]) (K=2048, N=1024, SK=2, atomic)
// 64x128 tiles (4 waves 2x2, acc 2x4 each), double-buffered LDS, one barrier/iter.
// Grid 4096, XCD-swizzled: same-(n,e,ksl) m-tiles share blockIdx%8 -> one XCD.
template <int MODE>
__global__ void __launch_bounds__(256) moe_gemm(
    const unsigned short* __restrict__ A, const unsigned short* __restrict__ B,
    const float* __restrict__ bias, const int* __restrict__ cnt,
    const int* __restrict__ btok, const float* __restrict__ bw,
    unsigned short* __restrict__ Hout, float* __restrict__ out) {
  constexpr int K   = (MODE == 0) ? D_DIM : H_DIM;
  constexpr int SK  = (MODE == 0) ? 1 : 2;
  constexpr int KS  = K / SK;
  constexpr int NIT = KS / 32;

  const int lin = blockIdx.x;                 // 0..4095
  const int glo = lin & 7;
  const int mt  = (lin >> 3) & 31;            // up to 32 m-tiles of 64 rows
  const int g   = ((lin >> 8) << 3) | glo;    // 0..127
  int nt, e, ksl;
  if (MODE == 0) { nt = g & 15; e = g >> 4; ksl = 0; }
  else           { nt = g & 7;  e = (g >> 3) & 7; ksl = g >> 6; }

  int base, ce, pcnt, total;
  expert_seg(cnt, e, base, ce, pcnt, total);
  if (mt * 64 >= pcnt) return;
  const int row0 = base + mt * 64;
  const int n0 = nt * 128;

  __shared__ __align__(16) unsigned short As[2][64 * 32];
  __shared__ __align__(16) unsigned short Bs[2][128 * 32];

  const int tid = threadIdx.x;
  const int lane = tid & 63;
  const int wv = tid >> 6;
  const int wm = wv >> 1;
  const int wn = wv & 1;

  const unsigned short* Ab = A + (size_t)row0 * K + ksl * KS;
  const unsigned short* Bb = B + (size_t)e * ((size_t)H_DIM * D_DIM) + (size_t)n0 * K + ksl * KS;

  f32x4 acc[2][4];
#pragma unroll
  for (int i = 0; i < 2; ++i)
#pragma unroll
    for (int j = 0; j < 4; ++j) acc[i][j] = (f32x4)(0.0f);

  const int subr = lane >> 2;        // 0..15
  const int ks = (lane & 3) * 8;     // 0,8,16,24 halfs
  const int fr = lane & 15;
  const int kq = (lane >> 4) * 8;

  auto stage = [&](int kt, int b) {
    const int k0 = kt * 32;
    {  // A: 4 chunks of 16 rows, one per wave
      const int r = wv * 16 + subr;
      const unsigned short* ga = Ab + (size_t)r * K + (k0 + ks);
      __builtin_amdgcn_global_load_lds(
          (__attribute__((address_space(1))) void*)ga,
          (__attribute__((address_space(3))) void*)(As[b] + wv * 16 * 32), 16, 0, 0);
    }
#pragma unroll
    for (int it = 0; it < 2; ++it) {  // B: 8 chunks, two per wave
      const int ci = wv + it * 4;
      const int r = ci * 16 + subr;
      const unsigned short* gb = Bb + (size_t)r * K + (k0 + ks);
      __builtin_amdgcn_global_load_lds(
          (__attribute__((address_space(1))) void*)gb,
          (__attribute__((address_space(3))) void*)(Bs[b] + ci * 16 * 32), 16, 0, 0);
    }
  };

  stage(0, 0);
  for (int i = 0; i < NIT; ++i) {
    const int b = i & 1;
    __syncthreads();                  // drains prefetch into buf b; protects WAR on b^1
    if (i + 1 < NIT) stage(i + 1, b ^ 1);
    bf16x8 av[2], bv[4];
#pragma unroll
    for (int mi = 0; mi < 2; ++mi)
      av[mi] = *(const bf16x8*)(As[b] + (wm * 32 + mi * 16 + fr) * 32 + kq);
#pragma unroll
    for (int ni = 0; ni < 4; ++ni)
      bv[ni] = *(const bf16x8*)(Bs[b] + (wn * 64 + ni * 16 + fr) * 32 + kq);
#pragma unroll
    for (int mi = 0; mi < 2; ++mi)
#pragma unroll
      for (int ni = 0; ni < 4; ++ni)
        acc[mi][ni] = __builtin_amdgcn_mfma_f32_16x16x32_bf16(av[mi], bv[ni], acc[mi][ni], 0, 0, 0);
  }

  if (MODE == 0) {
    const float* bb = bias + (size_t)e * H_DIM + n0;
#pragma unroll
    for (int mi = 0; mi < 2; ++mi) {
      const int rb = wm * 32 + mi * 16 + (lane >> 4) * 4;
#pragma unroll
      for (int r = 0; r < 4; ++r) {
        unsigned short* hp = Hout + (size_t)(row0 + rb + r) * H_DIM + n0;
#pragma unroll
        for (int ni = 0; ni < 4; ++ni) {
          const int col = wn * 64 + ni * 16 + fr;
          hp[col] = f2bf(gelu_tanh(acc[mi][ni][r] + bb[col]));
        }
      }
    }
  } else {
    const float* bb = bias + (size_t)e * D_DIM + n0;
#pragma unroll
    for (int mi = 0; mi < 2; ++mi) {
      const int rb = wm * 32 + mi * 16 + (lane >> 4) * 4;
#pragma unroll
      for (int r = 0; r < 4; ++r) {
        const int local = mt * 64 + rb + r;
        if (local < ce) {
          const int tok = btok[e * 2048 + local];
          const float w = bw[e * 2048 + local];
          float* op = out + (size_t)tok * D_DIM + n0;
#pragma unroll
          for (int ni = 0; ni < 4; ++ni) {
            const int col = wn * 64 + ni * 16 + fr;
            const float bias_once = (ksl == 0) ? bb[col] : 0.f;
            atomicAdd(op + col, w * (acc[mi][ni][r] + bias_once));
          }
        }
      }
    }
  }
}

extern "C" void kernel_launch(void* const* d_in, const int* in_sizes, int n_in,
                              void* d_out, int out_size, void* d_ws, size_t ws_size,
                              hipStream_t stream) {
  const float* moe_inp = (const float*)d_in[0];
  const float* Wg = (const float*)d_in[1];
  const float* bg = (const float*)d_in[2];
  const float* W1 = (const float*)d_in[3];
  const float* b1 = (const float*)d_in[4];
  const float* W2 = (const float*)d_in[5];
  const float* b2 = (const float*)d_in[6];
  float* out = (float*)d_out;

  char* ws = (char*)d_ws;
  int* cnt  = (int*)(ws + WS_CNT);
  int* btok = (int*)(ws + WS_BTOK);
  float* bw = (float*)(ws + WS_BW);
  unsigned short* Xg   = (unsigned short*)(ws + WS_XG);
  unsigned short* Hbuf = (unsigned short*)(ws + WS_HBUF);
  unsigned short* W1t  = (unsigned short*)(ws + WS_W1T);
  unsigned short* W2t  = (unsigned short*)(ws + WS_W2T);

  zero_kernel<<<dim3(2048), dim3(256), 0, stream>>>((float4*)out, cnt);
  gate_kernel<<<dim3(T_TOK / 4), dim3(256), 0, stream>>>(moe_inp, Wg, bg,
                                                         out + (size_t)T_TOK * D_DIM,
                                                         cnt, btok, bw);
  transpose_cvt<<<dim3(512, N_EXP, 2), dim3(256), 0, stream>>>(W1, W1t, W2, W2t);
  gather_cvt<<<dim3(MAXS), dim3(256), 0, stream>>>(moe_inp, cnt, btok, Xg);
  moe_gemm<0><<<dim3(4096), dim3(256), 0, stream>>>(
      Xg, W1t, b1, cnt, btok, bw, Hbuf, nullptr);
  moe_gemm<1><<<dim3(4096), dim3(256), 0, stream>>>(
      Hbuf, W2t, b2, cnt, btok, bw, nullptr, out);
}